// Round 2
// baseline (1177.481 us; speedup 1.0000x reference)
//
#include <hip/hip_runtime.h>

#define ALPHA 0.1f
#define FIN 128
#define HD 64
#define TD 10

// ---------------- init: deg=0, deg2=1 (self-loop weight), tmax=0 ----------------
__global__ __launch_bounds__(256) void k_init(float* deg, float* deg2, unsigned* tmaxb, int N) {
    int i = blockIdx.x * 256 + threadIdx.x;
    if (i == 0) *tmaxb = 0u;
    if (i < N) { deg[i] = 0.f; deg2[i] = 1.f; }
}

// ---------------- max(edge_time) via uint-bit atomicMax (times >= 0) ----------------
__global__ __launch_bounds__(256) void k_tmax(const float* __restrict__ t, unsigned* tmaxb, int E) {
    unsigned m = 0u;
    for (int i = blockIdx.x * 256 + threadIdx.x; i < E; i += gridDim.x * 256)
        m = max(m, __float_as_uint(t[i]));
    #pragma unroll
    for (int off = 32; off > 0; off >>= 1) {
        unsigned o = (unsigned)__shfl_down((int)m, off, 64);
        m = max(m, o);
    }
    if ((threadIdx.x & 63) == 0) atomicMax(tmaxb, m);
}

// ---------------- decay[e] = exp(-a*(tmax-t)); deg[row] += decay ----------------
__global__ __launch_bounds__(256) void k_decay(const float* __restrict__ t,
                                               const int* __restrict__ ei,
                                               const unsigned* __restrict__ tmaxb,
                                               float* __restrict__ ebuf,
                                               float* deg, int E) {
    int e = blockIdx.x * 256 + threadIdx.x;
    if (e >= E) return;
    float tmax = __uint_as_float(*tmaxb);
    float d = expf(-ALPHA * (tmax - t[e]));
    ebuf[e] = d;
    atomicAdd(&deg[ei[e]], d);
}

// ---------------- in-place a = a>0 ? rsqrt(a) : 0 ----------------
__global__ __launch_bounds__(256) void k_rsqrt(float* a, int N) {
    int i = blockIdx.x * 256 + threadIdx.x;
    if (i >= N) return;
    float v = a[i];
    a[i] = v > 0.f ? rsqrtf(v) : 0.f;
}

// ---------------- ew = dinv[row]*decay*dinv[col]; deg2[col] += ew ----------------
__global__ __launch_bounds__(256) void k_ew(const int* __restrict__ ei,
                                            const float* __restrict__ dinv,
                                            float* __restrict__ ebuf,
                                            float* deg2, int E) {
    int e = blockIdx.x * 256 + threadIdx.x;
    if (e >= E) return;
    int r = ei[e];
    int c = ei[E + e];
    float w = dinv[r] * ebuf[e] * dinv[c];
    ebuf[e] = w;
    atomicAdd(&deg2[c], w);
}

// ---------------- norm = dinv2[row]*ew*dinv2[col] ----------------
__global__ __launch_bounds__(256) void k_norm(const int* __restrict__ ei,
                                              const float* __restrict__ dinv2,
                                              float* __restrict__ ebuf, int E) {
    int e = blockIdx.x * 256 + threadIdx.x;
    if (e >= E) return;
    int r = ei[e];
    int c = ei[E + e];
    ebuf[e] *= dinv2[r] * dinv2[c];
}

// ---------------- h = x @ W1 (K=128); agg = dinv2^2 * h (self-loop init) ----------------
__global__ __launch_bounds__(256) void k_mm1(const float* __restrict__ x,
                                             const float* __restrict__ W1,
                                             const float* __restrict__ dinv2,
                                             float* __restrict__ hbuf,
                                             float* __restrict__ agg, int N) {
    __shared__ float Wl[FIN * HD];  // 32 KiB
    for (int i = threadIdx.x; i < FIN * HD; i += 256) Wl[i] = W1[i];
    __syncthreads();
    int lane = threadIdx.x & 63;
    int wid  = (blockIdx.x * 256 + threadIdx.x) >> 6;
    int nw   = (gridDim.x * 256) >> 6;
    for (int row = wid; row < N; row += nw) {
        const float4* xr = (const float4*)(x + (size_t)row * FIN);
        float acc = 0.f;
        #pragma unroll 8
        for (int k4 = 0; k4 < FIN / 4; ++k4) {
            float4 xv = xr[k4];  // wave-uniform broadcast load
            acc += xv.x * Wl[(k4 * 4 + 0) * HD + lane];
            acc += xv.y * Wl[(k4 * 4 + 1) * HD + lane];
            acc += xv.z * Wl[(k4 * 4 + 2) * HD + lane];
            acc += xv.w * Wl[(k4 * 4 + 3) * HD + lane];
        }
        hbuf[(size_t)row * HD + lane] = acc;
        float sn = dinv2[row];
        agg[(size_t)row * HD + lane] = sn * sn * acc;
    }
}

// ---------------- h = relu(aggin + b) @ W2 (K=64); aggout = dinv2^2 * h (in-place safe) ----------------
__global__ __launch_bounds__(256) void k_mm2(const float* __restrict__ aggin,
                                             const float* __restrict__ b,
                                             const float* __restrict__ W2,
                                             const float* __restrict__ dinv2,
                                             float* __restrict__ hbuf,
                                             float* __restrict__ aggout, int N) {
    __shared__ float Wl[HD * HD];  // 16 KiB
    __shared__ float bl[HD];
    for (int i = threadIdx.x; i < HD * HD; i += 256) Wl[i] = W2[i];
    if (threadIdx.x < HD) bl[threadIdx.x] = b[threadIdx.x];
    __syncthreads();
    int lane = threadIdx.x & 63;
    int wid  = (blockIdx.x * 256 + threadIdx.x) >> 6;
    int nw   = (gridDim.x * 256) >> 6;
    const float4* bv = (const float4*)bl;
    for (int row = wid; row < N; row += nw) {
        const float4* xr = (const float4*)(aggin + (size_t)row * HD);
        float acc = 0.f;
        #pragma unroll
        for (int k4 = 0; k4 < HD / 4; ++k4) {
            float4 xv = xr[k4];  // wave-uniform broadcast load (row fully read before write below)
            float4 bb = bv[k4];
            float h0 = fmaxf(xv.x + bb.x, 0.f);
            float h1 = fmaxf(xv.y + bb.y, 0.f);
            float h2 = fmaxf(xv.z + bb.z, 0.f);
            float h3 = fmaxf(xv.w + bb.w, 0.f);
            acc += h0 * Wl[(k4 * 4 + 0) * HD + lane];
            acc += h1 * Wl[(k4 * 4 + 1) * HD + lane];
            acc += h2 * Wl[(k4 * 4 + 2) * HD + lane];
            acc += h3 * Wl[(k4 * 4 + 3) * HD + lane];
        }
        hbuf[(size_t)row * HD + lane] = acc;
        float sn = dinv2[row];
        aggout[(size_t)row * HD + lane] = sn * sn * acc;
    }
}

// ---------------- agg[col][f] += norm[e] * h[row][f]  (wave per edge, lane = f) ----------------
__global__ __launch_bounds__(256) void k_scatter(const int* __restrict__ ei,
                                                 const float* __restrict__ ebuf,
                                                 const float* __restrict__ hbuf,
                                                 float* __restrict__ agg, int E) {
    long long idx = (long long)blockIdx.x * 256 + threadIdx.x;
    if (idx >= (long long)E * HD) return;
    int e = (int)(idx >> 6);
    int f = (int)(idx & 63);
    int r = ei[e];
    int c = ei[E + e];
    float w = ebuf[e];
    atomicAdd(&agg[(size_t)c * HD + f], w * hbuf[(size_t)r * HD + f]);
}

// ---------------- out = relu(agg + b2) @ Wout + bout ----------------
__global__ __launch_bounds__(256) void k_out(const float* __restrict__ agg,
                                             const float* __restrict__ b2,
                                             const float* __restrict__ Wout,
                                             const float* __restrict__ bout,
                                             float* __restrict__ out, int N) {
    __shared__ float Wl[HD * TD];
    __shared__ float bl[HD];
    __shared__ float bo[TD];
    for (int i = threadIdx.x; i < HD * TD; i += 256) Wl[i] = Wout[i];
    if (threadIdx.x < HD) bl[threadIdx.x] = b2[threadIdx.x];
    if (threadIdx.x < TD) bo[threadIdx.x] = bout[threadIdx.x];
    __syncthreads();
    int idx = blockIdx.x * 256 + threadIdx.x;
    if (idx >= N * TD) return;
    int n = idx / TD;
    int t = idx - n * TD;
    const float* a = agg + (size_t)n * HD;
    float acc = bo[t];
    #pragma unroll 8
    for (int k = 0; k < HD; ++k)
        acc += fmaxf(a[k] + bl[k], 0.f) * Wl[k * TD + t];
    out[idx] = acc;
}

extern "C" void kernel_launch(void* const* d_in, const int* in_sizes, int n_in,
                              void* d_out, int out_size, void* d_ws, size_t ws_size,
                              hipStream_t stream) {
    const float* x    = (const float*)d_in[0];
    const int*   ei   = (const int*)d_in[1];   // harness passes integer inputs as int32
    const float* et   = (const float*)d_in[2];
    const float* W1   = (const float*)d_in[3];
    const float* b1   = (const float*)d_in[4];
    const float* W2   = (const float*)d_in[5];
    const float* b2   = (const float*)d_in[6];
    const float* Wout = (const float*)d_in[7];
    const float* bout = (const float*)d_in[8];
    float*       out  = (float*)d_out;

    int N = in_sizes[0] / FIN;
    int E = in_sizes[2];

    char* w = (char*)d_ws;
    unsigned* tmaxb = (unsigned*)w;                     // 64 B slot
    float* ebuf = (float*)(w + 64);                     // E floats: decay -> ew -> norm
    float* deg  = ebuf + E;                             // N floats: deg -> dinv
    float* deg2 = deg + N;                              // N floats: deg2 -> dinv2
    float* hbuf = deg2 + N;                             // N*64 (reused both layers)
    float* agg  = hbuf + (size_t)N * HD;                // N*64 (reused both layers; mm2 in-place)

    int bN = (N + 255) / 256;
    int bE = (E + 255) / 256;
    long long totS = (long long)E * HD;
    int bS = (int)((totS + 255) / 256);

    k_init  <<<bN,   256, 0, stream>>>(deg, deg2, tmaxb, N);
    k_tmax  <<<1024, 256, 0, stream>>>(et, tmaxb, E);
    k_decay <<<bE,   256, 0, stream>>>(et, ei, tmaxb, ebuf, deg, E);
    k_rsqrt <<<bN,   256, 0, stream>>>(deg, N);
    k_ew    <<<bE,   256, 0, stream>>>(ei, deg, ebuf, deg2, E);
    k_rsqrt <<<bN,   256, 0, stream>>>(deg2, N);
    k_norm  <<<bE,   256, 0, stream>>>(ei, deg2, ebuf, E);

    k_mm1    <<<2048, 256, 0, stream>>>(x, W1, deg2, hbuf, agg, N);
    k_scatter<<<bS,   256, 0, stream>>>(ei, ebuf, hbuf, agg, E);
    k_mm2    <<<2048, 256, 0, stream>>>(agg, b1, W2, deg2, hbuf, agg, N);
    k_scatter<<<bS,   256, 0, stream>>>(ei, ebuf, hbuf, agg, E);
    k_out   <<<(N * TD + 255) / 256, 256, 0, stream>>>(agg, b2, Wout, bout, out, N);
}

// Round 3
// 1008.849 us; speedup vs baseline: 1.1672x; 1.1672x over previous
//
#include <hip/hip_runtime.h>

#define ALPHA 0.1f
#define FIN 128
#define HD 64
#define TD 10

// ---------------- init: deg=0, deg2=1 (self-loop), hist=0, tmax=0 ----------------
__global__ __launch_bounds__(256) void k_init(float* deg, float* deg2, int* hist,
                                              unsigned* tmaxb, int N) {
    int i = blockIdx.x * 256 + threadIdx.x;
    if (i == 0) *tmaxb = 0u;
    if (i < N) { deg[i] = 0.f; deg2[i] = 1.f; hist[i] = 0; }
}

// ---------------- max(edge_time): block-reduced, 1 atomic per block ----------------
__global__ __launch_bounds__(256) void k_tmax(const float* __restrict__ t, unsigned* tmaxb, int E) {
    __shared__ unsigned sm[4];
    unsigned m = 0u;
    for (int i = blockIdx.x * 256 + threadIdx.x; i < E; i += gridDim.x * 256)
        m = max(m, __float_as_uint(t[i]));
    #pragma unroll
    for (int off = 32; off > 0; off >>= 1)
        m = max(m, (unsigned)__shfl_down((int)m, off, 64));
    if ((threadIdx.x & 63) == 0) sm[threadIdx.x >> 6] = m;
    __syncthreads();
    if (threadIdx.x == 0) {
        m = max(max(sm[0], sm[1]), max(sm[2], sm[3]));
        atomicMax(tmaxb, m);
    }
}

// ------- decay[e]=exp(-a*(tmax-t)); deg[row]+=decay; hist[col]+=1 (fused) -------
__global__ __launch_bounds__(256) void k_decay(const float* __restrict__ t,
                                               const int* __restrict__ ei,
                                               const unsigned* __restrict__ tmaxb,
                                               float* __restrict__ ebuf,
                                               float* deg, int* hist, int E) {
    int e = blockIdx.x * 256 + threadIdx.x;
    if (e >= E) return;
    float tmax = __uint_as_float(*tmaxb);
    float d = expf(-ALPHA * (tmax - t[e]));
    ebuf[e] = d;
    atomicAdd(&deg[ei[e]], d);
    atomicAdd(&hist[ei[E + e]], 1);
}

// ---------------- in-place a = a>0 ? rsqrt(a) : 0 ----------------
__global__ __launch_bounds__(256) void k_rsqrt(float* a, int N) {
    int i = blockIdx.x * 256 + threadIdx.x;
    if (i >= N) return;
    float v = a[i];
    a[i] = v > 0.f ? rsqrtf(v) : 0.f;
}

// ---------------- ew = dinv[row]*decay*dinv[col]; deg2[col] += ew ----------------
__global__ __launch_bounds__(256) void k_ew(const int* __restrict__ ei,
                                            const float* __restrict__ dinv,
                                            float* __restrict__ ebuf,
                                            float* deg2, int E) {
    int e = blockIdx.x * 256 + threadIdx.x;
    if (e >= E) return;
    int r = ei[e];
    int c = ei[E + e];
    float w = dinv[r] * ebuf[e] * dinv[c];
    ebuf[e] = w;
    atomicAdd(&deg2[c], w);
}

// ------- single-block exclusive scan of hist -> rowptr, and off=rowptr copy -------
__global__ __launch_bounds__(1024) void k_scan(const int* __restrict__ hist,
                                               int* __restrict__ rowptr,
                                               int* __restrict__ off, int N) {
    __shared__ int part[1024];
    int tid = threadIdx.x;
    int chunk = (N + 1023) / 1024;
    int s = tid * chunk;
    int e = min(s + chunk, N);
    int sum = 0;
    for (int i = s; i < e; ++i) sum += hist[i];
    part[tid] = sum;
    __syncthreads();
    // Hillis-Steele inclusive scan
    for (int d = 1; d < 1024; d <<= 1) {
        int v = (tid >= d) ? part[tid - d] : 0;
        __syncthreads();
        part[tid] += v;
        __syncthreads();
    }
    int run = (tid > 0) ? part[tid - 1] : 0;
    for (int i = s; i < e; ++i) {
        rowptr[i] = run;
        off[i]    = run;
        run += hist[i];
    }
    if (s < N && e == N) rowptr[N] = run;
}

// ------- fill CSR: norm = ew*dinv2[r]*dinv2[c]; place (src,w) in dst bucket -------
__global__ __launch_bounds__(256) void k_fill(const int* __restrict__ ei,
                                              const float* __restrict__ ebuf,
                                              const float* __restrict__ dinv2,
                                              int* __restrict__ off,
                                              int* __restrict__ sidx,
                                              float* __restrict__ sw, int E) {
    int e = blockIdx.x * 256 + threadIdx.x;
    if (e >= E) return;
    int r = ei[e];
    int c = ei[E + e];
    float w = ebuf[e] * dinv2[r] * dinv2[c];
    int pos = atomicAdd(&off[c], 1);
    sidx[pos] = r;
    sw[pos]   = w;
}

// ---------------- h = x @ W1 (K=128), 4 rows per wave ----------------
__global__ __launch_bounds__(256) void k_mm1(const float* __restrict__ x,
                                             const float* __restrict__ W1,
                                             float* __restrict__ hbuf, int N) {
    __shared__ float Wl[FIN * HD];  // 32 KiB
    for (int i = threadIdx.x; i < FIN * HD; i += 256) Wl[i] = W1[i];
    __syncthreads();
    int lane = threadIdx.x & 63;
    int wid  = (blockIdx.x * 256 + threadIdx.x) >> 6;
    int r0   = wid * 4;
    if (r0 >= N) return;
    if (r0 + 3 < N) {
        const float4* x0 = (const float4*)(x + (size_t)(r0 + 0) * FIN);
        const float4* x1 = (const float4*)(x + (size_t)(r0 + 1) * FIN);
        const float4* x2 = (const float4*)(x + (size_t)(r0 + 2) * FIN);
        const float4* x3 = (const float4*)(x + (size_t)(r0 + 3) * FIN);
        float acc0 = 0.f, acc1 = 0.f, acc2 = 0.f, acc3 = 0.f;
        #pragma unroll 4
        for (int k4 = 0; k4 < FIN / 4; ++k4) {
            float4 a0 = x0[k4], a1 = x1[k4], a2 = x2[k4], a3 = x3[k4];
            float w0 = Wl[(k4 * 4 + 0) * HD + lane];
            float w1 = Wl[(k4 * 4 + 1) * HD + lane];
            float w2 = Wl[(k4 * 4 + 2) * HD + lane];
            float w3 = Wl[(k4 * 4 + 3) * HD + lane];
            acc0 += a0.x * w0 + a0.y * w1 + a0.z * w2 + a0.w * w3;
            acc1 += a1.x * w0 + a1.y * w1 + a1.z * w2 + a1.w * w3;
            acc2 += a2.x * w0 + a2.y * w1 + a2.z * w2 + a2.w * w3;
            acc3 += a3.x * w0 + a3.y * w1 + a3.z * w2 + a3.w * w3;
        }
        hbuf[(size_t)(r0 + 0) * HD + lane] = acc0;
        hbuf[(size_t)(r0 + 1) * HD + lane] = acc1;
        hbuf[(size_t)(r0 + 2) * HD + lane] = acc2;
        hbuf[(size_t)(r0 + 3) * HD + lane] = acc3;
    } else {
        for (int r = r0; r < N; ++r) {
            const float4* xr = (const float4*)(x + (size_t)r * FIN);
            float acc = 0.f;
            for (int k4 = 0; k4 < FIN / 4; ++k4) {
                float4 a = xr[k4];
                acc += a.x * Wl[(k4 * 4 + 0) * HD + lane];
                acc += a.y * Wl[(k4 * 4 + 1) * HD + lane];
                acc += a.z * Wl[(k4 * 4 + 2) * HD + lane];
                acc += a.w * Wl[(k4 * 4 + 3) * HD + lane];
            }
            hbuf[(size_t)r * HD + lane] = acc;
        }
    }
}

// ---------------- h2 = relu(agg + b) @ W2 (K=64), 4 rows per wave ----------------
__global__ __launch_bounds__(256) void k_mm2(const float* __restrict__ agg,
                                             const float* __restrict__ b,
                                             const float* __restrict__ W2,
                                             float* __restrict__ hbuf, int N) {
    __shared__ float Wl[HD * HD];  // 16 KiB
    __shared__ float bl[HD];
    for (int i = threadIdx.x; i < HD * HD; i += 256) Wl[i] = W2[i];
    if (threadIdx.x < HD) bl[threadIdx.x] = b[threadIdx.x];
    __syncthreads();
    int lane = threadIdx.x & 63;
    int wid  = (blockIdx.x * 256 + threadIdx.x) >> 6;
    int r0   = wid * 4;
    if (r0 >= N) return;
    const float4* bv = (const float4*)bl;
    if (r0 + 3 < N) {
        const float4* x0 = (const float4*)(agg + (size_t)(r0 + 0) * HD);
        const float4* x1 = (const float4*)(agg + (size_t)(r0 + 1) * HD);
        const float4* x2 = (const float4*)(agg + (size_t)(r0 + 2) * HD);
        const float4* x3 = (const float4*)(agg + (size_t)(r0 + 3) * HD);
        float acc0 = 0.f, acc1 = 0.f, acc2 = 0.f, acc3 = 0.f;
        #pragma unroll 4
        for (int k4 = 0; k4 < HD / 4; ++k4) {
            float4 bb = bv[k4];
            float4 a0 = x0[k4], a1 = x1[k4], a2 = x2[k4], a3 = x3[k4];
            float w0 = Wl[(k4 * 4 + 0) * HD + lane];
            float w1 = Wl[(k4 * 4 + 1) * HD + lane];
            float w2 = Wl[(k4 * 4 + 2) * HD + lane];
            float w3 = Wl[(k4 * 4 + 3) * HD + lane];
            acc0 += fmaxf(a0.x + bb.x, 0.f) * w0 + fmaxf(a0.y + bb.y, 0.f) * w1
                  + fmaxf(a0.z + bb.z, 0.f) * w2 + fmaxf(a0.w + bb.w, 0.f) * w3;
            acc1 += fmaxf(a1.x + bb.x, 0.f) * w0 + fmaxf(a1.y + bb.y, 0.f) * w1
                  + fmaxf(a1.z + bb.z, 0.f) * w2 + fmaxf(a1.w + bb.w, 0.f) * w3;
            acc2 += fmaxf(a2.x + bb.x, 0.f) * w0 + fmaxf(a2.y + bb.y, 0.f) * w1
                  + fmaxf(a2.z + bb.z, 0.f) * w2 + fmaxf(a2.w + bb.w, 0.f) * w3;
            acc3 += fmaxf(a3.x + bb.x, 0.f) * w0 + fmaxf(a3.y + bb.y, 0.f) * w1
                  + fmaxf(a3.z + bb.z, 0.f) * w2 + fmaxf(a3.w + bb.w, 0.f) * w3;
        }
        hbuf[(size_t)(r0 + 0) * HD + lane] = acc0;
        hbuf[(size_t)(r0 + 1) * HD + lane] = acc1;
        hbuf[(size_t)(r0 + 2) * HD + lane] = acc2;
        hbuf[(size_t)(r0 + 3) * HD + lane] = acc3;
    } else {
        for (int r = r0; r < N; ++r) {
            const float4* xr = (const float4*)(agg + (size_t)r * HD);
            float acc = 0.f;
            for (int k4 = 0; k4 < HD / 4; ++k4) {
                float4 a = xr[k4];
                float4 bb = bv[k4];
                acc += fmaxf(a.x + bb.x, 0.f) * Wl[(k4 * 4 + 0) * HD + lane];
                acc += fmaxf(a.y + bb.y, 0.f) * Wl[(k4 * 4 + 1) * HD + lane];
                acc += fmaxf(a.z + bb.z, 0.f) * Wl[(k4 * 4 + 2) * HD + lane];
                acc += fmaxf(a.w + bb.w, 0.f) * Wl[(k4 * 4 + 3) * HD + lane];
            }
            hbuf[(size_t)r * HD + lane] = acc;
        }
    }
}

// ------- CSR gather: agg[c] = dinv2[c]^2*h[c] + sum_e w[e]*h[src[e]]  (wave/node) -------
__global__ __launch_bounds__(256) void k_agg(const int* __restrict__ rowptr,
                                             const int* __restrict__ sidx,
                                             const float* __restrict__ sw,
                                             const float* __restrict__ h,
                                             const float* __restrict__ dinv2,
                                             float* __restrict__ agg, int N) {
    int lane = threadIdx.x & 63;
    int node = (blockIdx.x * 256 + threadIdx.x) >> 6;
    if (node >= N) return;
    int s = rowptr[node];
    int e = rowptr[node + 1];
    float sn = dinv2[node];
    float acc = sn * sn * h[(size_t)node * HD + lane];
    int p = s;
    for (; p + 4 <= e; p += 4) {
        int  s0 = sidx[p + 0], s1 = sidx[p + 1], s2 = sidx[p + 2], s3 = sidx[p + 3];
        float w0 = sw[p + 0], w1 = sw[p + 1], w2 = sw[p + 2], w3 = sw[p + 3];
        float v0 = h[(size_t)s0 * HD + lane];
        float v1 = h[(size_t)s1 * HD + lane];
        float v2 = h[(size_t)s2 * HD + lane];
        float v3 = h[(size_t)s3 * HD + lane];
        acc += w0 * v0 + w1 * v1 + w2 * v2 + w3 * v3;
    }
    for (; p < e; ++p)
        acc += sw[p] * h[(size_t)sidx[p] * HD + lane];
    agg[(size_t)node * HD + lane] = acc;
}

// ---------------- out = relu(agg + b2) @ Wout + bout ----------------
__global__ __launch_bounds__(256) void k_out(const float* __restrict__ agg,
                                             const float* __restrict__ b2,
                                             const float* __restrict__ Wout,
                                             const float* __restrict__ bout,
                                             float* __restrict__ out, int N) {
    __shared__ float Wl[HD * TD];
    __shared__ float bl[HD];
    __shared__ float bo[TD];
    for (int i = threadIdx.x; i < HD * TD; i += 256) Wl[i] = Wout[i];
    if (threadIdx.x < HD) bl[threadIdx.x] = b2[threadIdx.x];
    if (threadIdx.x < TD) bo[threadIdx.x] = bout[threadIdx.x];
    __syncthreads();
    int idx = blockIdx.x * 256 + threadIdx.x;
    if (idx >= N * TD) return;
    int n = idx / TD;
    int t = idx - n * TD;
    const float* a = agg + (size_t)n * HD;
    float acc = bo[t];
    #pragma unroll 8
    for (int k = 0; k < HD; ++k)
        acc += fmaxf(a[k] + bl[k], 0.f) * Wl[k * TD + t];
    out[idx] = acc;
}

extern "C" void kernel_launch(void* const* d_in, const int* in_sizes, int n_in,
                              void* d_out, int out_size, void* d_ws, size_t ws_size,
                              hipStream_t stream) {
    const float* x    = (const float*)d_in[0];
    const int*   ei   = (const int*)d_in[1];   // harness passes integers as int32
    const float* et   = (const float*)d_in[2];
    const float* W1   = (const float*)d_in[3];
    const float* b1   = (const float*)d_in[4];
    const float* W2   = (const float*)d_in[5];
    const float* b2   = (const float*)d_in[6];
    const float* Wout = (const float*)d_in[7];
    const float* bout = (const float*)d_in[8];
    float*       out  = (float*)d_out;

    int N = in_sizes[0] / FIN;
    int E = in_sizes[2];

    // --- workspace layout, 256B-aligned regions ---
    char*  base = (char*)d_ws;
    size_t ofs  = 0;
    auto alloc = [&](size_t bytes) -> char* {
        char* p = base + ofs;
        ofs = (ofs + bytes + 255) & ~(size_t)255;
        return p;
    };
    unsigned* tmaxb  = (unsigned*)alloc(64);
    float*    ebuf   = (float*)alloc((size_t)E * 4);        // decay -> ew
    float*    deg    = (float*)alloc((size_t)N * 4);        // deg -> dinv
    float*    deg2   = (float*)alloc((size_t)N * 4);        // deg2 -> dinv2
    int*      hist   = (int*)alloc((size_t)N * 4);          // dst histogram
    int*      rowptr = (int*)alloc((size_t)(N + 1) * 4);
    int*      offb   = (int*)alloc((size_t)N * 4);          // running fill cursor
    int*      sidx   = (int*)alloc((size_t)E * 4);          // CSR src indices
    float*    sw     = (float*)alloc((size_t)E * 4);        // CSR weights
    float*    hbuf   = (float*)alloc((size_t)N * HD * 4);
    float*    agg    = (float*)alloc((size_t)N * HD * 4);

    int bN  = (N + 255) / 256;
    int bE  = (E + 255) / 256;
    int bW4 = (N + 15) / 16;                  // 4 rows/wave, 4 waves/block
    int bWN = (N * HD + 255) / 256;           // wave per node

    k_init <<<bN,  256, 0, stream>>>(deg, deg2, hist, tmaxb, N);
    k_tmax <<<256, 256, 0, stream>>>(et, tmaxb, E);
    k_decay<<<bE,  256, 0, stream>>>(et, ei, tmaxb, ebuf, deg, hist, E);
    k_rsqrt<<<bN,  256, 0, stream>>>(deg, N);
    k_ew   <<<bE,  256, 0, stream>>>(ei, deg, ebuf, deg2, E);
    k_rsqrt<<<bN,  256, 0, stream>>>(deg2, N);
    k_scan <<<1,  1024, 0, stream>>>(hist, rowptr, offb, N);
    k_fill <<<bE,  256, 0, stream>>>(ei, ebuf, deg2, offb, sidx, sw, E);

    k_mm1  <<<bW4, 256, 0, stream>>>(x, W1, hbuf, N);
    k_agg  <<<bWN, 256, 0, stream>>>(rowptr, sidx, sw, hbuf, deg2, agg, N);
    k_mm2  <<<bW4, 256, 0, stream>>>(agg, b1, W2, hbuf, N);
    k_agg  <<<bWN, 256, 0, stream>>>(rowptr, sidx, sw, hbuf, deg2, agg, N);
    k_out  <<<(N * TD + 255) / 256, 256, 0, stream>>>(agg, b2, Wout, bout, out, N);
}

// Round 4
// 793.967 us; speedup vs baseline: 1.4830x; 1.2706x over previous
//
#include <hip/hip_runtime.h>

#define ALPHA 0.1f
#define FIN 128
#define HD 64
#define TD 10
#define SCAN_ELEMS 1024

// ---------------- init: deg=0, deg2=1 (self-loop), hist=0, tmax=0 ----------------
__global__ __launch_bounds__(256) void k_init(float* deg, float* deg2, int* hist,
                                              unsigned* tmaxb, int N) {
    int i = blockIdx.x * 256 + threadIdx.x;
    if (i == 0) *tmaxb = 0u;
    if (i < N) { deg[i] = 0.f; deg2[i] = 1.f; hist[i] = 0; }
}

// ---------------- max(edge_time): block-reduced, 1 atomic per block ----------------
__global__ __launch_bounds__(256) void k_tmax(const float* __restrict__ t, unsigned* tmaxb, int E) {
    __shared__ unsigned sm[4];
    unsigned m = 0u;
    for (int i = blockIdx.x * 256 + threadIdx.x; i < E; i += gridDim.x * 256)
        m = max(m, __float_as_uint(t[i]));
    #pragma unroll
    for (int off = 32; off > 0; off >>= 1)
        m = max(m, (unsigned)__shfl_down((int)m, off, 64));
    if ((threadIdx.x & 63) == 0) sm[threadIdx.x >> 6] = m;
    __syncthreads();
    if (threadIdx.x == 0) {
        m = max(max(sm[0], sm[1]), max(sm[2], sm[3]));
        atomicMax(tmaxb, m);
    }
}

// ------- decay[e]=exp(-a*(tmax-t)); deg[row]+=decay; hist[col]+=1 (fused) -------
__global__ __launch_bounds__(256) void k_decay(const float* __restrict__ t,
                                               const int* __restrict__ ei,
                                               const unsigned* __restrict__ tmaxb,
                                               float* __restrict__ ebuf,
                                               float* deg, int* hist, int E) {
    int e = blockIdx.x * 256 + threadIdx.x;
    if (e >= E) return;
    float tmax = __uint_as_float(*tmaxb);
    float d = expf(-ALPHA * (tmax - t[e]));
    ebuf[e] = d;
    atomicAdd(&deg[ei[e]], d);
    atomicAdd(&hist[ei[E + e]], 1);
}

// ---------------- in-place a = a>0 ? rsqrt(a) : 0 ----------------
__global__ __launch_bounds__(256) void k_rsqrt(float* a, int N) {
    int i = blockIdx.x * 256 + threadIdx.x;
    if (i >= N) return;
    float v = a[i];
    a[i] = v > 0.f ? rsqrtf(v) : 0.f;
}

// ---------------- ew = dinv[row]*decay*dinv[col]; deg2[col] += ew ----------------
__global__ __launch_bounds__(256) void k_ew(const int* __restrict__ ei,
                                            const float* __restrict__ dinv,
                                            float* __restrict__ ebuf,
                                            float* deg2, int E) {
    int e = blockIdx.x * 256 + threadIdx.x;
    if (e >= E) return;
    int r = ei[e];
    int c = ei[E + e];
    float w = dinv[r] * ebuf[e] * dinv[c];
    ebuf[e] = w;
    atomicAdd(&deg2[c], w);
}

// ---------------- scan phase A: per-block sum of 1024-elem hist chunk ----------------
__global__ __launch_bounds__(256) void k_scan_a(const int* __restrict__ hist,
                                                int* __restrict__ bsum, int N) {
    __shared__ int sm[4];
    int base = blockIdx.x * SCAN_ELEMS + threadIdx.x * 4;
    int s = 0;
    if (base + 3 < N) {
        int4 v = *(const int4*)(hist + base);
        s = v.x + v.y + v.z + v.w;
    } else {
        for (int i = base; i < N && i < base + 4; ++i) s += hist[i];
    }
    #pragma unroll
    for (int off = 32; off > 0; off >>= 1) s += __shfl_down(s, off, 64);
    if ((threadIdx.x & 63) == 0) sm[threadIdx.x >> 6] = s;
    __syncthreads();
    if (threadIdx.x == 0) bsum[blockIdx.x] = sm[0] + sm[1] + sm[2] + sm[3];
}

// ------- scan phase B: 1 block scans <=1024 partials; writes rowptr[N]=total -------
__global__ __launch_bounds__(1024) void k_scan_b(const int* __restrict__ bsum,
                                                 int* __restrict__ boff,
                                                 int NB, int* __restrict__ rowptrN) {
    __shared__ int part[1024];
    int tid = threadIdx.x;
    int v = (tid < NB) ? bsum[tid] : 0;
    part[tid] = v;
    __syncthreads();
    for (int d = 1; d < 1024; d <<= 1) {
        int t = (tid >= d) ? part[tid - d] : 0;
        __syncthreads();
        part[tid] += t;
        __syncthreads();
    }
    if (tid < NB) boff[tid] = part[tid] - v;        // exclusive block offset
    if (tid == 1023) *rowptrN = part[1023];          // grand total
}

// ------- scan phase C: block-local scan + block offset -> rowptr, off ----------
__global__ __launch_bounds__(256) void k_scan_c(const int* __restrict__ hist,
                                                const int* __restrict__ boff,
                                                int* __restrict__ rowptr,
                                                int* __restrict__ off, int N) {
    __shared__ int part[256];
    int base = blockIdx.x * SCAN_ELEMS + threadIdx.x * 4;
    int vv[4] = {0, 0, 0, 0};
    if (base + 3 < N) {
        int4 v = *(const int4*)(hist + base);
        vv[0] = v.x; vv[1] = v.y; vv[2] = v.z; vv[3] = v.w;
    } else {
        for (int i = 0; i < 4; ++i) if (base + i < N) vv[i] = hist[base + i];
    }
    int s = vv[0] + vv[1] + vv[2] + vv[3];
    part[threadIdx.x] = s;
    __syncthreads();
    for (int d = 1; d < 256; d <<= 1) {
        int t = (threadIdx.x >= d) ? part[threadIdx.x - d] : 0;
        __syncthreads();
        part[threadIdx.x] += t;
        __syncthreads();
    }
    int run = boff[blockIdx.x] + part[threadIdx.x] - s;  // exclusive prefix
    int pp[4];
    pp[0] = run;
    pp[1] = pp[0] + vv[0];
    pp[2] = pp[1] + vv[1];
    pp[3] = pp[2] + vv[2];
    if (base + 3 < N) {
        *(int4*)(rowptr + base) = make_int4(pp[0], pp[1], pp[2], pp[3]);
        *(int4*)(off + base)    = make_int4(pp[0], pp[1], pp[2], pp[3]);
    } else {
        for (int i = 0; i < 4; ++i)
            if (base + i < N) { rowptr[base + i] = pp[i]; off[base + i] = pp[i]; }
    }
}

// ------- fill CSR: norm = ew*dinv2[r]*dinv2[c]; place (src,w) in dst bucket -------
__global__ __launch_bounds__(256) void k_fill(const int* __restrict__ ei,
                                              const float* __restrict__ ebuf,
                                              const float* __restrict__ dinv2,
                                              int* __restrict__ off,
                                              int* __restrict__ sidx,
                                              float* __restrict__ sw, int E) {
    int e = blockIdx.x * 256 + threadIdx.x;
    if (e >= E) return;
    int r = ei[e];
    int c = ei[E + e];
    float w = ebuf[e] * dinv2[r] * dinv2[c];
    int pos = atomicAdd(&off[c], 1);
    sidx[pos] = r;
    sw[pos]   = w;
}

// ---------------- h = x @ W1 (K=128), 4 rows per wave ----------------
__global__ __launch_bounds__(256) void k_mm1(const float* __restrict__ x,
                                             const float* __restrict__ W1,
                                             float* __restrict__ hbuf, int N) {
    __shared__ float Wl[FIN * HD];  // 32 KiB
    for (int i = threadIdx.x; i < FIN * HD; i += 256) Wl[i] = W1[i];
    __syncthreads();
    int lane = threadIdx.x & 63;
    int wid  = (blockIdx.x * 256 + threadIdx.x) >> 6;
    int r0   = wid * 4;
    if (r0 >= N) return;
    if (r0 + 3 < N) {
        const float4* x0 = (const float4*)(x + (size_t)(r0 + 0) * FIN);
        const float4* x1 = (const float4*)(x + (size_t)(r0 + 1) * FIN);
        const float4* x2 = (const float4*)(x + (size_t)(r0 + 2) * FIN);
        const float4* x3 = (const float4*)(x + (size_t)(r0 + 3) * FIN);
        float acc0 = 0.f, acc1 = 0.f, acc2 = 0.f, acc3 = 0.f;
        #pragma unroll 4
        for (int k4 = 0; k4 < FIN / 4; ++k4) {
            float4 a0 = x0[k4], a1 = x1[k4], a2 = x2[k4], a3 = x3[k4];
            float w0 = Wl[(k4 * 4 + 0) * HD + lane];
            float w1 = Wl[(k4 * 4 + 1) * HD + lane];
            float w2 = Wl[(k4 * 4 + 2) * HD + lane];
            float w3 = Wl[(k4 * 4 + 3) * HD + lane];
            acc0 += a0.x * w0 + a0.y * w1 + a0.z * w2 + a0.w * w3;
            acc1 += a1.x * w0 + a1.y * w1 + a1.z * w2 + a1.w * w3;
            acc2 += a2.x * w0 + a2.y * w1 + a2.z * w2 + a2.w * w3;
            acc3 += a3.x * w0 + a3.y * w1 + a3.z * w2 + a3.w * w3;
        }
        hbuf[(size_t)(r0 + 0) * HD + lane] = acc0;
        hbuf[(size_t)(r0 + 1) * HD + lane] = acc1;
        hbuf[(size_t)(r0 + 2) * HD + lane] = acc2;
        hbuf[(size_t)(r0 + 3) * HD + lane] = acc3;
    } else {
        for (int r = r0; r < N; ++r) {
            const float4* xr = (const float4*)(x + (size_t)r * FIN);
            float acc = 0.f;
            for (int k4 = 0; k4 < FIN / 4; ++k4) {
                float4 a = xr[k4];
                acc += a.x * Wl[(k4 * 4 + 0) * HD + lane];
                acc += a.y * Wl[(k4 * 4 + 1) * HD + lane];
                acc += a.z * Wl[(k4 * 4 + 2) * HD + lane];
                acc += a.w * Wl[(k4 * 4 + 3) * HD + lane];
            }
            hbuf[(size_t)r * HD + lane] = acc;
        }
    }
}

// ---------------- h2 = relu(agg + b) @ W2 (K=64), 4 rows per wave ----------------
__global__ __launch_bounds__(256) void k_mm2(const float* __restrict__ agg,
                                             const float* __restrict__ b,
                                             const float* __restrict__ W2,
                                             float* __restrict__ hbuf, int N) {
    __shared__ float Wl[HD * HD];  // 16 KiB
    __shared__ float bl[HD];
    for (int i = threadIdx.x; i < HD * HD; i += 256) Wl[i] = W2[i];
    if (threadIdx.x < HD) bl[threadIdx.x] = b[threadIdx.x];
    __syncthreads();
    int lane = threadIdx.x & 63;
    int wid  = (blockIdx.x * 256 + threadIdx.x) >> 6;
    int r0   = wid * 4;
    if (r0 >= N) return;
    const float4* bv = (const float4*)bl;
    if (r0 + 3 < N) {
        const float4* x0 = (const float4*)(agg + (size_t)(r0 + 0) * HD);
        const float4* x1 = (const float4*)(agg + (size_t)(r0 + 1) * HD);
        const float4* x2 = (const float4*)(agg + (size_t)(r0 + 2) * HD);
        const float4* x3 = (const float4*)(agg + (size_t)(r0 + 3) * HD);
        float acc0 = 0.f, acc1 = 0.f, acc2 = 0.f, acc3 = 0.f;
        #pragma unroll 4
        for (int k4 = 0; k4 < HD / 4; ++k4) {
            float4 bb = bv[k4];
            float4 a0 = x0[k4], a1 = x1[k4], a2 = x2[k4], a3 = x3[k4];
            float w0 = Wl[(k4 * 4 + 0) * HD + lane];
            float w1 = Wl[(k4 * 4 + 1) * HD + lane];
            float w2 = Wl[(k4 * 4 + 2) * HD + lane];
            float w3 = Wl[(k4 * 4 + 3) * HD + lane];
            acc0 += fmaxf(a0.x + bb.x, 0.f) * w0 + fmaxf(a0.y + bb.y, 0.f) * w1
                  + fmaxf(a0.z + bb.z, 0.f) * w2 + fmaxf(a0.w + bb.w, 0.f) * w3;
            acc1 += fmaxf(a1.x + bb.x, 0.f) * w0 + fmaxf(a1.y + bb.y, 0.f) * w1
                  + fmaxf(a1.z + bb.z, 0.f) * w2 + fmaxf(a1.w + bb.w, 0.f) * w3;
            acc2 += fmaxf(a2.x + bb.x, 0.f) * w0 + fmaxf(a2.y + bb.y, 0.f) * w1
                  + fmaxf(a2.z + bb.z, 0.f) * w2 + fmaxf(a2.w + bb.w, 0.f) * w3;
            acc3 += fmaxf(a3.x + bb.x, 0.f) * w0 + fmaxf(a3.y + bb.y, 0.f) * w1
                  + fmaxf(a3.z + bb.z, 0.f) * w2 + fmaxf(a3.w + bb.w, 0.f) * w3;
        }
        hbuf[(size_t)(r0 + 0) * HD + lane] = acc0;
        hbuf[(size_t)(r0 + 1) * HD + lane] = acc1;
        hbuf[(size_t)(r0 + 2) * HD + lane] = acc2;
        hbuf[(size_t)(r0 + 3) * HD + lane] = acc3;
    } else {
        for (int r = r0; r < N; ++r) {
            const float4* xr = (const float4*)(agg + (size_t)r * HD);
            float acc = 0.f;
            for (int k4 = 0; k4 < HD / 4; ++k4) {
                float4 a = xr[k4];
                float4 bb = bv[k4];
                acc += fmaxf(a.x + bb.x, 0.f) * Wl[(k4 * 4 + 0) * HD + lane];
                acc += fmaxf(a.y + bb.y, 0.f) * Wl[(k4 * 4 + 1) * HD + lane];
                acc += fmaxf(a.z + bb.z, 0.f) * Wl[(k4 * 4 + 2) * HD + lane];
                acc += fmaxf(a.w + bb.w, 0.f) * Wl[(k4 * 4 + 3) * HD + lane];
            }
            hbuf[(size_t)r * HD + lane] = acc;
        }
    }
}

// ------- CSR gather: agg[c] = dinv2[c]^2*h[c] + sum_e w[e]*h[src[e]]  (wave/node) -------
__global__ __launch_bounds__(256) void k_agg(const int* __restrict__ rowptr,
                                             const int* __restrict__ sidx,
                                             const float* __restrict__ sw,
                                             const float* __restrict__ h,
                                             const float* __restrict__ dinv2,
                                             float* __restrict__ agg, int N) {
    int lane = threadIdx.x & 63;
    int node = (blockIdx.x * 256 + threadIdx.x) >> 6;
    if (node >= N) return;
    int s = rowptr[node];
    int e = rowptr[node + 1];
    float sn = dinv2[node];
    float acc = sn * sn * h[(size_t)node * HD + lane];
    int p = s;
    for (; p + 4 <= e; p += 4) {
        int  s0 = sidx[p + 0], s1 = sidx[p + 1], s2 = sidx[p + 2], s3 = sidx[p + 3];
        float w0 = sw[p + 0], w1 = sw[p + 1], w2 = sw[p + 2], w3 = sw[p + 3];
        float v0 = h[(size_t)s0 * HD + lane];
        float v1 = h[(size_t)s1 * HD + lane];
        float v2 = h[(size_t)s2 * HD + lane];
        float v3 = h[(size_t)s3 * HD + lane];
        acc += w0 * v0 + w1 * v1 + w2 * v2 + w3 * v3;
    }
    for (; p < e; ++p)
        acc += sw[p] * h[(size_t)sidx[p] * HD + lane];
    agg[(size_t)node * HD + lane] = acc;
}

// ---------------- out = relu(agg + b2) @ Wout + bout ----------------
__global__ __launch_bounds__(256) void k_out(const float* __restrict__ agg,
                                             const float* __restrict__ b2,
                                             const float* __restrict__ Wout,
                                             const float* __restrict__ bout,
                                             float* __restrict__ out, int N) {
    __shared__ float Wl[HD * TD];
    __shared__ float bl[HD];
    __shared__ float bo[TD];
    for (int i = threadIdx.x; i < HD * TD; i += 256) Wl[i] = Wout[i];
    if (threadIdx.x < HD) bl[threadIdx.x] = b2[threadIdx.x];
    if (threadIdx.x < TD) bo[threadIdx.x] = bout[threadIdx.x];
    __syncthreads();
    int idx = blockIdx.x * 256 + threadIdx.x;
    if (idx >= N * TD) return;
    int n = idx / TD;
    int t = idx - n * TD;
    const float* a = agg + (size_t)n * HD;
    float acc = bo[t];
    #pragma unroll 8
    for (int k = 0; k < HD; ++k)
        acc += fmaxf(a[k] + bl[k], 0.f) * Wl[k * TD + t];
    out[idx] = acc;
}

extern "C" void kernel_launch(void* const* d_in, const int* in_sizes, int n_in,
                              void* d_out, int out_size, void* d_ws, size_t ws_size,
                              hipStream_t stream) {
    const float* x    = (const float*)d_in[0];
    const int*   ei   = (const int*)d_in[1];   // harness passes integers as int32
    const float* et   = (const float*)d_in[2];
    const float* W1   = (const float*)d_in[3];
    const float* b1   = (const float*)d_in[4];
    const float* W2   = (const float*)d_in[5];
    const float* b2   = (const float*)d_in[6];
    const float* Wout = (const float*)d_in[7];
    const float* bout = (const float*)d_in[8];
    float*       out  = (float*)d_out;

    int N = in_sizes[0] / FIN;
    int E = in_sizes[2];
    int NB = (N + SCAN_ELEMS - 1) / SCAN_ELEMS;   // scan blocks (98 for N=100K)

    // --- workspace layout, 256B-aligned regions ---
    char*  base = (char*)d_ws;
    size_t ofs  = 0;
    auto alloc = [&](size_t bytes) -> char* {
        char* p = base + ofs;
        ofs = (ofs + bytes + 255) & ~(size_t)255;
        return p;
    };
    unsigned* tmaxb  = (unsigned*)alloc(64);
    float*    ebuf   = (float*)alloc((size_t)E * 4);        // decay -> ew
    float*    deg    = (float*)alloc((size_t)N * 4);        // deg -> dinv
    float*    deg2   = (float*)alloc((size_t)N * 4);        // deg2 -> dinv2
    int*      hist   = (int*)alloc((size_t)N * 4);          // dst histogram
    int*      rowptr = (int*)alloc((size_t)(N + 1) * 4);
    int*      offb   = (int*)alloc((size_t)N * 4);          // running fill cursor
    int*      bsum   = (int*)alloc((size_t)1024 * 4);       // scan partials
    int*      boff   = (int*)alloc((size_t)1024 * 4);       // scan block offsets
    int*      sidx   = (int*)alloc((size_t)E * 4);          // CSR src indices
    float*    sw     = (float*)alloc((size_t)E * 4);        // CSR weights
    float*    hbuf   = (float*)alloc((size_t)N * HD * 4);
    float*    agg    = (float*)alloc((size_t)N * HD * 4);

    int bN  = (N + 255) / 256;
    int bE  = (E + 255) / 256;
    int bW4 = (N + 15) / 16;                  // 4 rows/wave, 4 waves/block
    int bWN = (N * HD + 255) / 256;           // wave per node

    k_init  <<<bN,  256, 0, stream>>>(deg, deg2, hist, tmaxb, N);
    k_tmax  <<<256, 256, 0, stream>>>(et, tmaxb, E);
    k_decay <<<bE,  256, 0, stream>>>(et, ei, tmaxb, ebuf, deg, hist, E);
    k_rsqrt <<<bN,  256, 0, stream>>>(deg, N);
    k_ew    <<<bE,  256, 0, stream>>>(ei, deg, ebuf, deg2, E);
    k_rsqrt <<<bN,  256, 0, stream>>>(deg2, N);
    k_scan_a<<<NB,  256, 0, stream>>>(hist, bsum, N);
    k_scan_b<<<1,  1024, 0, stream>>>(bsum, boff, NB, rowptr + N);
    k_scan_c<<<NB,  256, 0, stream>>>(hist, boff, rowptr, offb, N);
    k_fill  <<<bE,  256, 0, stream>>>(ei, ebuf, deg2, offb, sidx, sw, E);

    k_mm1   <<<bW4, 256, 0, stream>>>(x, W1, hbuf, N);
    k_agg   <<<bWN, 256, 0, stream>>>(rowptr, sidx, sw, hbuf, deg2, agg, N);
    k_mm2   <<<bW4, 256, 0, stream>>>(agg, b1, W2, hbuf, N);
    k_agg   <<<bWN, 256, 0, stream>>>(rowptr, sidx, sw, hbuf, deg2, agg, N);
    k_out   <<<(N * TD + 255) / 256, 256, 0, stream>>>(agg, b2, Wout, bout, out, N);
}

// Round 5
// 699.861 us; speedup vs baseline: 1.6824x; 1.1345x over previous
//
#include <hip/hip_runtime.h>

#define ALPHA 0.1f
#define FIN 128
#define HD 64
#define TD 10
#define SCAN_ELEMS 1024

// ---------------- init: deg=0, deg2=1 (self-loop), hist=0, tmax=0 ----------------
__global__ __launch_bounds__(256) void k_init(float* deg, float* deg2, int* hist,
                                              unsigned* tmaxb, int N) {
    int i = blockIdx.x * 256 + threadIdx.x;
    if (i == 0) *tmaxb = 0u;
    if (i < N) { deg[i] = 0.f; deg2[i] = 1.f; hist[i] = 0; }
}

// ---------------- max(edge_time): block-reduced, 1 atomic per block ----------------
__global__ __launch_bounds__(256) void k_tmax(const float* __restrict__ t, unsigned* tmaxb, int E) {
    __shared__ unsigned sm[4];
    unsigned m = 0u;
    for (int i = blockIdx.x * 256 + threadIdx.x; i < E; i += gridDim.x * 256)
        m = max(m, __float_as_uint(t[i]));
    #pragma unroll
    for (int off = 32; off > 0; off >>= 1)
        m = max(m, (unsigned)__shfl_down((int)m, off, 64));
    if ((threadIdx.x & 63) == 0) sm[threadIdx.x >> 6] = m;
    __syncthreads();
    if (threadIdx.x == 0) {
        m = max(max(sm[0], sm[1]), max(sm[2], sm[3]));
        atomicMax(tmaxb, m);
    }
}

// ------- decay[e]=exp(-a*(tmax-t)); deg[row]+=decay; hist[col]+=1 (fused) -------
__global__ __launch_bounds__(256) void k_decay(const float* __restrict__ t,
                                               const int* __restrict__ ei,
                                               const unsigned* __restrict__ tmaxb,
                                               float* __restrict__ ebuf,
                                               float* deg, int* hist, int E) {
    int e = blockIdx.x * 256 + threadIdx.x;
    if (e >= E) return;
    float tmax = __uint_as_float(*tmaxb);
    float d = expf(-ALPHA * (tmax - t[e]));
    ebuf[e] = d;
    atomicAdd(&deg[ei[e]], d);
    atomicAdd(&hist[ei[E + e]], 1);
}

// ---------------- in-place a = a>0 ? rsqrt(a) : 0 ----------------
__global__ __launch_bounds__(256) void k_rsqrt(float* a, int N) {
    int i = blockIdx.x * 256 + threadIdx.x;
    if (i >= N) return;
    float v = a[i];
    a[i] = v > 0.f ? rsqrtf(v) : 0.f;
}

// ---------------- ew = dinv[row]*decay*dinv[col]; deg2[col] += ew ----------------
__global__ __launch_bounds__(256) void k_ew(const int* __restrict__ ei,
                                            const float* __restrict__ dinv,
                                            float* __restrict__ ebuf,
                                            float* deg2, int E) {
    int e = blockIdx.x * 256 + threadIdx.x;
    if (e >= E) return;
    int r = ei[e];
    int c = ei[E + e];
    float w = dinv[r] * ebuf[e] * dinv[c];
    ebuf[e] = w;
    atomicAdd(&deg2[c], w);
}

// ---------------- scan phase A: per-block sum of 1024-elem hist chunk ----------------
__global__ __launch_bounds__(256) void k_scan_a(const int* __restrict__ hist,
                                                int* __restrict__ bsum, int N) {
    __shared__ int sm[4];
    int base = blockIdx.x * SCAN_ELEMS + threadIdx.x * 4;
    int s = 0;
    if (base + 3 < N) {
        int4 v = *(const int4*)(hist + base);
        s = v.x + v.y + v.z + v.w;
    } else {
        for (int i = base; i < N && i < base + 4; ++i) s += hist[i];
    }
    #pragma unroll
    for (int off = 32; off > 0; off >>= 1) s += __shfl_down(s, off, 64);
    if ((threadIdx.x & 63) == 0) sm[threadIdx.x >> 6] = s;
    __syncthreads();
    if (threadIdx.x == 0) bsum[blockIdx.x] = sm[0] + sm[1] + sm[2] + sm[3];
}

// ------- scan phase B: 1 block scans <=1024 partials; writes rowptr[N]=total -------
__global__ __launch_bounds__(1024) void k_scan_b(const int* __restrict__ bsum,
                                                 int* __restrict__ boff,
                                                 int NB, int* __restrict__ rowptrN) {
    __shared__ int part[1024];
    int tid = threadIdx.x;
    int v = (tid < NB) ? bsum[tid] : 0;
    part[tid] = v;
    __syncthreads();
    for (int d = 1; d < 1024; d <<= 1) {
        int t = (tid >= d) ? part[tid - d] : 0;
        __syncthreads();
        part[tid] += t;
        __syncthreads();
    }
    if (tid < NB) boff[tid] = part[tid] - v;        // exclusive block offset
    if (tid == 1023) *rowptrN = part[1023];          // grand total
}

// ------- scan phase C: block-local scan + block offset -> rowptr, off ----------
__global__ __launch_bounds__(256) void k_scan_c(const int* __restrict__ hist,
                                                const int* __restrict__ boff,
                                                int* __restrict__ rowptr,
                                                int* __restrict__ off, int N) {
    __shared__ int part[256];
    int base = blockIdx.x * SCAN_ELEMS + threadIdx.x * 4;
    int vv[4] = {0, 0, 0, 0};
    if (base + 3 < N) {
        int4 v = *(const int4*)(hist + base);
        vv[0] = v.x; vv[1] = v.y; vv[2] = v.z; vv[3] = v.w;
    } else {
        for (int i = 0; i < 4; ++i) if (base + i < N) vv[i] = hist[base + i];
    }
    int s = vv[0] + vv[1] + vv[2] + vv[3];
    part[threadIdx.x] = s;
    __syncthreads();
    for (int d = 1; d < 256; d <<= 1) {
        int t = (threadIdx.x >= d) ? part[threadIdx.x - d] : 0;
        __syncthreads();
        part[threadIdx.x] += t;
        __syncthreads();
    }
    int run = boff[blockIdx.x] + part[threadIdx.x] - s;  // exclusive prefix
    int pp[4];
    pp[0] = run;
    pp[1] = pp[0] + vv[0];
    pp[2] = pp[1] + vv[1];
    pp[3] = pp[2] + vv[2];
    if (base + 3 < N) {
        *(int4*)(rowptr + base) = make_int4(pp[0], pp[1], pp[2], pp[3]);
        *(int4*)(off + base)    = make_int4(pp[0], pp[1], pp[2], pp[3]);
    } else {
        for (int i = 0; i < 4; ++i)
            if (base + i < N) { rowptr[base + i] = pp[i]; off[base + i] = pp[i]; }
    }
}

// ------- fill CSR: norm = ew*dinv2[r]*dinv2[c]; place (src,w) in dst bucket -------
__global__ __launch_bounds__(256) void k_fill(const int* __restrict__ ei,
                                              const float* __restrict__ ebuf,
                                              const float* __restrict__ dinv2,
                                              int* __restrict__ off,
                                              int* __restrict__ sidx,
                                              float* __restrict__ sw, int E) {
    int e = blockIdx.x * 256 + threadIdx.x;
    if (e >= E) return;
    int r = ei[e];
    int c = ei[E + e];
    float w = ebuf[e] * dinv2[r] * dinv2[c];
    int pos = atomicAdd(&off[c], 1);
    sidx[pos] = r;
    sw[pos]   = w;
}

// -------- h = x @ W1 (K=128): W column in regs, x tile in LDS (64 rows) --------
__global__ __launch_bounds__(256) void k_mm1(const float* __restrict__ x,
                                             const float* __restrict__ W1,
                                             float* __restrict__ hbuf, int N) {
    __shared__ float xl[64 * FIN];  // 32 KiB
    int tid  = threadIdx.x;
    int lane = tid & 63;
    int wv   = tid >> 6;
    float Wreg[FIN];                 // lane's output column of W1 (static idx -> VGPR)
    #pragma unroll
    for (int k = 0; k < FIN; ++k) Wreg[k] = W1[k * HD + lane];
    int tile0 = blockIdx.x * 64;
    if (tile0 >= N) return;
    int nrow = min(64, N - tile0);
    const float4* gx = (const float4*)(x + (size_t)tile0 * FIN);
    float4* lx = (float4*)xl;
    int nv = nrow * (FIN / 4);
    for (int i = tid; i < nv; i += 256) lx[i] = gx[i];   // coalesced stage
    __syncthreads();
    int rend = min(wv * 16 + 16, nrow);
    for (int r = wv * 16; r < rend; ++r) {
        const float4* xr = (const float4*)(xl + r * FIN);
        float acc = 0.f;
        #pragma unroll
        for (int k4 = 0; k4 < FIN / 4; ++k4) {
            float4 v = xr[k4];       // LDS broadcast read
            acc += v.x * Wreg[4 * k4 + 0] + v.y * Wreg[4 * k4 + 1]
                 + v.z * Wreg[4 * k4 + 2] + v.w * Wreg[4 * k4 + 3];
        }
        hbuf[(size_t)(tile0 + r) * HD + lane] = acc;
    }
}

// -- h2 = relu(agg + b1) @ W2 (K=64): W col in regs, relu fused into LDS stage --
__global__ __launch_bounds__(256) void k_mm2(const float* __restrict__ agg,
                                             const float* __restrict__ b1,
                                             const float* __restrict__ W2,
                                             float* __restrict__ hbuf, int N) {
    __shared__ float xl[128 * HD];  // 32 KiB
    int tid  = threadIdx.x;
    int lane = tid & 63;
    int wv   = tid >> 6;
    float Wreg[HD];
    #pragma unroll
    for (int k = 0; k < HD; ++k) Wreg[k] = W2[k * HD + lane];
    float4 bb = ((const float4*)b1)[tid & 15];   // (tid+256j)&15 == tid&15
    int tile0 = blockIdx.x * 128;
    if (tile0 >= N) return;
    int nrow = min(128, N - tile0);
    const float4* gx = (const float4*)(agg + (size_t)tile0 * HD);
    float4* lx = (float4*)xl;
    int nv = nrow * (HD / 4);
    for (int i = tid; i < nv; i += 256) {
        float4 v = gx[i];
        v.x = fmaxf(v.x + bb.x, 0.f);
        v.y = fmaxf(v.y + bb.y, 0.f);
        v.z = fmaxf(v.z + bb.z, 0.f);
        v.w = fmaxf(v.w + bb.w, 0.f);
        lx[i] = v;                   // relu(agg+b) staged once
    }
    __syncthreads();
    int rend = min(wv * 32 + 32, nrow);
    for (int r = wv * 32; r < rend; ++r) {
        const float4* xr = (const float4*)(xl + r * HD);
        float acc = 0.f;
        #pragma unroll
        for (int k4 = 0; k4 < HD / 4; ++k4) {
            float4 v = xr[k4];
            acc += v.x * Wreg[4 * k4 + 0] + v.y * Wreg[4 * k4 + 1]
                 + v.z * Wreg[4 * k4 + 2] + v.w * Wreg[4 * k4 + 3];
        }
        hbuf[(size_t)(tile0 + r) * HD + lane] = acc;
    }
}

// ------- CSR gather: agg[c] = dinv2[c]^2*h[c] + sum_e w[e]*h[src[e]]  (wave/node) -------
__global__ __launch_bounds__(256) void k_agg(const int* __restrict__ rowptr,
                                             const int* __restrict__ sidx,
                                             const float* __restrict__ sw,
                                             const float* __restrict__ h,
                                             const float* __restrict__ dinv2,
                                             float* __restrict__ agg, int N) {
    int lane = threadIdx.x & 63;
    int node = (blockIdx.x * 256 + threadIdx.x) >> 6;
    if (node >= N) return;
    int s = rowptr[node];
    int e = rowptr[node + 1];
    float sn = dinv2[node];
    float acc = sn * sn * h[(size_t)node * HD + lane];
    int p = s;
    for (; p + 4 <= e; p += 4) {
        int  s0 = sidx[p + 0], s1 = sidx[p + 1], s2 = sidx[p + 2], s3 = sidx[p + 3];
        float w0 = sw[p + 0], w1 = sw[p + 1], w2 = sw[p + 2], w3 = sw[p + 3];
        float v0 = h[(size_t)s0 * HD + lane];
        float v1 = h[(size_t)s1 * HD + lane];
        float v2 = h[(size_t)s2 * HD + lane];
        float v3 = h[(size_t)s3 * HD + lane];
        acc += w0 * v0 + w1 * v1 + w2 * v2 + w3 * v3;
    }
    for (; p < e; ++p)
        acc += sw[p] * h[(size_t)sidx[p] * HD + lane];
    agg[(size_t)node * HD + lane] = acc;
}

// ---------------- out = relu(agg + b2) @ Wout + bout ----------------
__global__ __launch_bounds__(256) void k_out(const float* __restrict__ agg,
                                             const float* __restrict__ b2,
                                             const float* __restrict__ Wout,
                                             const float* __restrict__ bout,
                                             float* __restrict__ out, int N) {
    __shared__ float Wl[HD * TD];
    __shared__ float bl[HD];
    __shared__ float bo[TD];
    for (int i = threadIdx.x; i < HD * TD; i += 256) Wl[i] = Wout[i];
    if (threadIdx.x < HD) bl[threadIdx.x] = b2[threadIdx.x];
    if (threadIdx.x < TD) bo[threadIdx.x] = bout[threadIdx.x];
    __syncthreads();
    int idx = blockIdx.x * 256 + threadIdx.x;
    if (idx >= N * TD) return;
    int n = idx / TD;
    int t = idx - n * TD;
    const float* a = agg + (size_t)n * HD;
    float acc = bo[t];
    #pragma unroll 8
    for (int k = 0; k < HD; ++k)
        acc += fmaxf(a[k] + bl[k], 0.f) * Wl[k * TD + t];
    out[idx] = acc;
}

extern "C" void kernel_launch(void* const* d_in, const int* in_sizes, int n_in,
                              void* d_out, int out_size, void* d_ws, size_t ws_size,
                              hipStream_t stream) {
    const float* x    = (const float*)d_in[0];
    const int*   ei   = (const int*)d_in[1];   // harness passes integers as int32
    const float* et   = (const float*)d_in[2];
    const float* W1   = (const float*)d_in[3];
    const float* b1   = (const float*)d_in[4];
    const float* W2   = (const float*)d_in[5];
    const float* b2   = (const float*)d_in[6];
    const float* Wout = (const float*)d_in[7];
    const float* bout = (const float*)d_in[8];
    float*       out  = (float*)d_out;

    int N = in_sizes[0] / FIN;
    int E = in_sizes[2];
    int NB = (N + SCAN_ELEMS - 1) / SCAN_ELEMS;   // scan blocks (98 for N=100K)

    // --- workspace layout, 256B-aligned regions ---
    char*  base = (char*)d_ws;
    size_t ofs  = 0;
    auto alloc = [&](size_t bytes) -> char* {
        char* p = base + ofs;
        ofs = (ofs + bytes + 255) & ~(size_t)255;
        return p;
    };
    unsigned* tmaxb  = (unsigned*)alloc(64);
    float*    ebuf   = (float*)alloc((size_t)E * 4);        // decay -> ew
    float*    deg    = (float*)alloc((size_t)N * 4);        // deg -> dinv
    float*    deg2   = (float*)alloc((size_t)N * 4);        // deg2 -> dinv2
    int*      hist   = (int*)alloc((size_t)N * 4);          // dst histogram
    int*      rowptr = (int*)alloc((size_t)(N + 1) * 4);
    int*      offb   = (int*)alloc((size_t)N * 4);          // running fill cursor
    int*      bsum   = (int*)alloc((size_t)1024 * 4);       // scan partials
    int*      boff   = (int*)alloc((size_t)1024 * 4);       // scan block offsets
    int*      sidx   = (int*)alloc((size_t)E * 4);          // CSR src indices
    float*    sw     = (float*)alloc((size_t)E * 4);        // CSR weights
    float*    hbuf   = (float*)alloc((size_t)N * HD * 4);
    float*    agg    = (float*)alloc((size_t)N * HD * 4);

    int bN   = (N + 255) / 256;
    int bE   = (E + 255) / 256;
    int bT1  = (N + 63) / 64;                 // mm1 tiles
    int bT2  = (N + 127) / 128;               // mm2 tiles
    int bWN  = (N * HD + 255) / 256;          // wave per node

    k_init  <<<bN,  256, 0, stream>>>(deg, deg2, hist, tmaxb, N);
    k_tmax  <<<256, 256, 0, stream>>>(et, tmaxb, E);
    k_decay <<<bE,  256, 0, stream>>>(et, ei, tmaxb, ebuf, deg, hist, E);
    k_rsqrt <<<bN,  256, 0, stream>>>(deg, N);
    k_ew    <<<bE,  256, 0, stream>>>(ei, deg, ebuf, deg2, E);
    k_rsqrt <<<bN,  256, 0, stream>>>(deg2, N);
    k_scan_a<<<NB,  256, 0, stream>>>(hist, bsum, N);
    k_scan_b<<<1,  1024, 0, stream>>>(bsum, boff, NB, rowptr + N);
    k_scan_c<<<NB,  256, 0, stream>>>(hist, boff, rowptr, offb, N);
    k_fill  <<<bE,  256, 0, stream>>>(ei, ebuf, deg2, offb, sidx, sw, E);

    k_mm1   <<<bT1, 256, 0, stream>>>(x, W1, hbuf, N);
    k_agg   <<<bWN, 256, 0, stream>>>(rowptr, sidx, sw, hbuf, deg2, agg, N);
    k_mm2   <<<bT2, 256, 0, stream>>>(agg, b1, W2, hbuf, N);
    k_agg   <<<bWN, 256, 0, stream>>>(rowptr, sidx, sw, hbuf, deg2, agg, N);
    k_out   <<<(N * TD + 255) / 256, 256, 0, stream>>>(agg, b2, Wout, bout, out, N);
}

// Round 6
// 516.171 us; speedup vs baseline: 2.2812x; 1.3559x over previous
//
#include <hip/hip_runtime.h>

#define ALPHA 0.1f
#define FIN 128
#define HD 64
#define TD 10
#define SCAN_ELEMS 1024
#define CHUNK 16384           // nodes per LDS chunk (2^14)
#define SPLIT 16              // sub-blocks per chunk

// ---------------- init: tmax=0 ----------------
__global__ __launch_bounds__(64) void k_init(unsigned* tmaxb) {
    if (threadIdx.x == 0) *tmaxb = 0u;
}

// ---------------- max(edge_time): block-reduced, 1 atomic per block ----------------
__global__ __launch_bounds__(256) void k_tmax(const float* __restrict__ t, unsigned* tmaxb, int E) {
    __shared__ unsigned sm[4];
    unsigned m = 0u;
    for (int i = blockIdx.x * 256 + threadIdx.x; i < E; i += gridDim.x * 256)
        m = max(m, __float_as_uint(t[i]));
    #pragma unroll
    for (int off = 32; off > 0; off >>= 1)
        m = max(m, (unsigned)__shfl_down((int)m, off, 64));
    if ((threadIdx.x & 63) == 0) sm[threadIdx.x >> 6] = m;
    __syncthreads();
    if (threadIdx.x == 0) {
        m = max(max(sm[0], sm[1]), max(sm[2], sm[3]));
        atomicMax(tmaxb, m);
    }
}

// ------ chunked LDS-privatized deg(row,decay-weighted) + hist(col) ------
// grid = NCHUNK*SPLIT blocks of 1024; block (c,b): chunk c, edge-slice b.
// Also writes ebuf[e] = decay (chunk-0 group covers all edges).
__global__ __launch_bounds__(1024) void k_deghist(const int* __restrict__ ei,
                                                  const float* __restrict__ t,
                                                  const unsigned* __restrict__ tmaxb,
                                                  float* __restrict__ ebuf,
                                                  float* __restrict__ privD,
                                                  int* __restrict__ privH,
                                                  int E, int N) {
    __shared__ float ldsD[CHUNK];   // 64 KiB
    __shared__ int   ldsH[CHUNK];   // 64 KiB
    int c = blockIdx.x / SPLIT;
    int b = blockIdx.x - c * SPLIT;
    int base = c * CHUNK;
    for (int i = threadIdx.x; i < CHUNK; i += 1024) { ldsD[i] = 0.f; ldsH[i] = 0; }
    __syncthreads();
    float tmax = __uint_as_float(*tmaxb);
    long long e0 = (long long)E * b / SPLIT;
    long long e1 = (long long)E * (b + 1) / SPLIT;
    for (long long e = e0 + threadIdx.x; e < e1; e += 1024) {
        int r  = ei[e];
        int cc = ei[E + e];
        float d = expf(-ALPHA * (tmax - t[e]));
        if (c == 0) ebuf[e] = d;
        unsigned rr = (unsigned)(r - base);
        if (rr < CHUNK) atomicAdd(&ldsD[rr], d);
        unsigned cr = (unsigned)(cc - base);
        if (cr < CHUNK) atomicAdd(&ldsH[cr], 1);
    }
    __syncthreads();
    float* pd = privD + ((size_t)c * SPLIT + b) * CHUNK;
    int*   ph = privH + ((size_t)c * SPLIT + b) * CHUNK;
    for (int i = threadIdx.x; i < CHUNK; i += 1024) { pd[i] = ldsD[i]; ph[i] = ldsH[i]; }
}

// ------ reduce the SPLIT private copies -> deg, hist ------
__global__ __launch_bounds__(256) void k_deghist_red(const float* __restrict__ privD,
                                                     const int* __restrict__ privH,
                                                     float* __restrict__ deg,
                                                     int* __restrict__ hist, int N) {
    int n = blockIdx.x * 256 + threadIdx.x;
    if (n >= N) return;
    int c = n >> 14;              // /CHUNK
    int i = n & (CHUNK - 1);
    const float* pd = privD + ((size_t)c * SPLIT) * CHUNK + i;
    const int*   ph = privH + ((size_t)c * SPLIT) * CHUNK + i;
    float s = 0.f; int h = 0;
    #pragma unroll
    for (int b = 0; b < SPLIT; ++b) {
        s += pd[(size_t)b * CHUNK];
        h += ph[(size_t)b * CHUNK];
    }
    deg[n] = s;
    hist[n] = h;
}

// ---------------- in-place a = a>0 ? rsqrt(a) : 0 ----------------
__global__ __launch_bounds__(256) void k_rsqrt(float* a, int N) {
    int i = blockIdx.x * 256 + threadIdx.x;
    if (i >= N) return;
    float v = a[i];
    a[i] = v > 0.f ? rsqrtf(v) : 0.f;
}

// ---------------- scan phase A: per-block sum of 1024-elem hist chunk ----------------
__global__ __launch_bounds__(256) void k_scan_a(const int* __restrict__ hist,
                                                int* __restrict__ bsum, int N) {
    __shared__ int sm[4];
    int base = blockIdx.x * SCAN_ELEMS + threadIdx.x * 4;
    int s = 0;
    if (base + 3 < N) {
        int4 v = *(const int4*)(hist + base);
        s = v.x + v.y + v.z + v.w;
    } else {
        for (int i = base; i < N && i < base + 4; ++i) s += hist[i];
    }
    #pragma unroll
    for (int off = 32; off > 0; off >>= 1) s += __shfl_down(s, off, 64);
    if ((threadIdx.x & 63) == 0) sm[threadIdx.x >> 6] = s;
    __syncthreads();
    if (threadIdx.x == 0) bsum[blockIdx.x] = sm[0] + sm[1] + sm[2] + sm[3];
}

// ------- scan phase B: 1 block scans <=1024 partials; writes rowptr[N]=total -------
__global__ __launch_bounds__(1024) void k_scan_b(const int* __restrict__ bsum,
                                                 int* __restrict__ boff,
                                                 int NB, int* __restrict__ rowptrN) {
    __shared__ int part[1024];
    int tid = threadIdx.x;
    int v = (tid < NB) ? bsum[tid] : 0;
    part[tid] = v;
    __syncthreads();
    for (int d = 1; d < 1024; d <<= 1) {
        int t = (tid >= d) ? part[tid - d] : 0;
        __syncthreads();
        part[tid] += t;
        __syncthreads();
    }
    if (tid < NB) boff[tid] = part[tid] - v;
    if (tid == 1023) *rowptrN = part[1023];
}

// ------- scan phase C: block-local scan + block offset -> rowptr, off ----------
__global__ __launch_bounds__(256) void k_scan_c(const int* __restrict__ hist,
                                                const int* __restrict__ boff,
                                                int* __restrict__ rowptr,
                                                int* __restrict__ off, int N) {
    __shared__ int part[256];
    int base = blockIdx.x * SCAN_ELEMS + threadIdx.x * 4;
    int vv[4] = {0, 0, 0, 0};
    if (base + 3 < N) {
        int4 v = *(const int4*)(hist + base);
        vv[0] = v.x; vv[1] = v.y; vv[2] = v.z; vv[3] = v.w;
    } else {
        for (int i = 0; i < 4; ++i) if (base + i < N) vv[i] = hist[base + i];
    }
    int s = vv[0] + vv[1] + vv[2] + vv[3];
    part[threadIdx.x] = s;
    __syncthreads();
    for (int d = 1; d < 256; d <<= 1) {
        int t = (threadIdx.x >= d) ? part[threadIdx.x - d] : 0;
        __syncthreads();
        part[threadIdx.x] += t;
        __syncthreads();
    }
    int run = boff[blockIdx.x] + part[threadIdx.x] - s;
    int pp[4];
    pp[0] = run;
    pp[1] = pp[0] + vv[0];
    pp[2] = pp[1] + vv[1];
    pp[3] = pp[2] + vv[2];
    if (base + 3 < N) {
        *(int4*)(rowptr + base) = make_int4(pp[0], pp[1], pp[2], pp[3]);
        *(int4*)(off + base)    = make_int4(pp[0], pp[1], pp[2], pp[3]);
    } else {
        for (int i = 0; i < 4; ++i)
            if (base + i < N) { rowptr[base + i] = pp[i]; off[base + i] = pp[i]; }
    }
}

// ------- fused: ew = dinv[r]*decay*dinv[c]; CSR place (r, ew) in dst bucket -------
// (dinv2 factors moved into k_agg via g = dinv2*h; CSR weight is RAW ew)
__global__ __launch_bounds__(256) void k_ewfill(const int* __restrict__ ei,
                                                const float* __restrict__ ebuf,
                                                const float* __restrict__ dinv,
                                                int* __restrict__ off,
                                                int* __restrict__ sidx,
                                                float* __restrict__ sw, int E) {
    int e = blockIdx.x * 256 + threadIdx.x;
    if (e >= E) return;
    int r = ei[e];
    int c = ei[E + e];
    float w = dinv[r] * ebuf[e] * dinv[c];
    int pos = atomicAdd(&off[c], 1);
    sidx[pos] = r;
    sw[pos]   = w;
}

// ------- deg2[c] = 1 + segment_sum(sw over bucket c)  (no atomics) -------
__global__ __launch_bounds__(256) void k_deg2(const int* __restrict__ rowptr,
                                              const float* __restrict__ sw,
                                              float* __restrict__ deg2, int N) {
    int n = blockIdx.x * 256 + threadIdx.x;
    if (n >= N) return;
    int s = rowptr[n], e = rowptr[n + 1];
    float a = 1.f;
    for (int p = s; p < e; ++p) a += sw[p];
    deg2[n] = a;
}

// -------- g1 = dinv2 * (x @ W1): W column in regs, x tile in LDS, 4 acc chains --------
__global__ __launch_bounds__(256) void k_mm1(const float* __restrict__ x,
                                             const float* __restrict__ W1,
                                             const float* __restrict__ dinv2,
                                             float* __restrict__ gbuf, int N) {
    __shared__ float xl[64 * FIN];  // 32 KiB
    int tid  = threadIdx.x;
    int lane = tid & 63;
    int wv   = tid >> 6;
    float Wreg[FIN];
    #pragma unroll
    for (int k = 0; k < FIN; ++k) Wreg[k] = W1[k * HD + lane];
    int tile0 = blockIdx.x * 64;
    if (tile0 >= N) return;
    int nrow = min(64, N - tile0);
    const float4* gx = (const float4*)(x + (size_t)tile0 * FIN);
    float4* lx = (float4*)xl;
    int nv = nrow * (FIN / 4);
    for (int i = tid; i < nv; i += 256) lx[i] = gx[i];
    __syncthreads();
    for (int r = wv; r < nrow; r += 4) {
        const float4* xr = (const float4*)(xl + r * FIN);
        float a0 = 0.f, a1 = 0.f, a2 = 0.f, a3 = 0.f;
        #pragma unroll
        for (int k4 = 0; k4 < FIN / 4; ++k4) {
            float4 v = xr[k4];
            a0 += v.x * Wreg[4 * k4 + 0];
            a1 += v.y * Wreg[4 * k4 + 1];
            a2 += v.z * Wreg[4 * k4 + 2];
            a3 += v.w * Wreg[4 * k4 + 3];
        }
        float sn = dinv2[tile0 + r];
        gbuf[(size_t)(tile0 + r) * HD + lane] = sn * ((a0 + a1) + (a2 + a3));
    }
}

// -- g2 = dinv2 * (relu(agg+b1) @ W2): W col in regs, relu fused into LDS stage --
__global__ __launch_bounds__(256) void k_mm2(const float* __restrict__ agg,
                                             const float* __restrict__ b1,
                                             const float* __restrict__ W2,
                                             const float* __restrict__ dinv2,
                                             float* __restrict__ gbuf, int N) {
    __shared__ float xl[128 * HD];  // 32 KiB
    int tid  = threadIdx.x;
    int lane = tid & 63;
    int wv   = tid >> 6;
    float Wreg[HD];
    #pragma unroll
    for (int k = 0; k < HD; ++k) Wreg[k] = W2[k * HD + lane];
    float4 bb = ((const float4*)b1)[tid & 15];
    int tile0 = blockIdx.x * 128;
    if (tile0 >= N) return;
    int nrow = min(128, N - tile0);
    const float4* gx = (const float4*)(agg + (size_t)tile0 * HD);
    float4* lx = (float4*)xl;
    int nv = nrow * (HD / 4);
    for (int i = tid; i < nv; i += 256) {
        float4 v = gx[i];
        v.x = fmaxf(v.x + bb.x, 0.f);
        v.y = fmaxf(v.y + bb.y, 0.f);
        v.z = fmaxf(v.z + bb.z, 0.f);
        v.w = fmaxf(v.w + bb.w, 0.f);
        lx[i] = v;
    }
    __syncthreads();
    for (int r = wv; r < nrow; r += 4) {
        const float4* xr = (const float4*)(xl + r * HD);
        float a0 = 0.f, a1 = 0.f, a2 = 0.f, a3 = 0.f;
        #pragma unroll
        for (int k4 = 0; k4 < HD / 4; ++k4) {
            float4 v = xr[k4];
            a0 += v.x * Wreg[4 * k4 + 0];
            a1 += v.y * Wreg[4 * k4 + 1];
            a2 += v.z * Wreg[4 * k4 + 2];
            a3 += v.w * Wreg[4 * k4 + 3];
        }
        float sn = dinv2[tile0 + r];
        gbuf[(size_t)(tile0 + r) * HD + lane] = sn * ((a0 + a1) + (a2 + a3));
    }
}

// ------- CSR gather: agg[c] = dinv2[c]*( g[c] + sum_e ew[e]*g[src[e]] ) -------
__global__ __launch_bounds__(256) void k_agg(const int* __restrict__ rowptr,
                                             const int* __restrict__ sidx,
                                             const float* __restrict__ sw,
                                             const float* __restrict__ g,
                                             const float* __restrict__ dinv2,
                                             float* __restrict__ agg, int N) {
    int lane = threadIdx.x & 63;
    int node = (blockIdx.x * 256 + threadIdx.x) >> 6;
    if (node >= N) return;
    int s = rowptr[node];
    int e = rowptr[node + 1];
    float a0 = g[(size_t)node * HD + lane];
    float a1 = 0.f, a2 = 0.f, a3 = 0.f;
    int p = s;
    for (; p + 4 <= e; p += 4) {
        int  s0 = sidx[p + 0], s1 = sidx[p + 1], s2 = sidx[p + 2], s3 = sidx[p + 3];
        float w0 = sw[p + 0], w1 = sw[p + 1], w2 = sw[p + 2], w3 = sw[p + 3];
        a0 += w0 * g[(size_t)s0 * HD + lane];
        a1 += w1 * g[(size_t)s1 * HD + lane];
        a2 += w2 * g[(size_t)s2 * HD + lane];
        a3 += w3 * g[(size_t)s3 * HD + lane];
    }
    for (; p < e; ++p)
        a0 += sw[p] * g[(size_t)sidx[p] * HD + lane];
    agg[(size_t)node * HD + lane] = dinv2[node] * ((a0 + a1) + (a2 + a3));
}

// ---------------- out = relu(agg + b2) @ Wout + bout ----------------
__global__ __launch_bounds__(256) void k_out(const float* __restrict__ agg,
                                             const float* __restrict__ b2,
                                             const float* __restrict__ Wout,
                                             const float* __restrict__ bout,
                                             float* __restrict__ out, int N) {
    __shared__ float Wl[HD * TD];
    __shared__ float bl[HD];
    __shared__ float bo[TD];
    for (int i = threadIdx.x; i < HD * TD; i += 256) Wl[i] = Wout[i];
    if (threadIdx.x < HD) bl[threadIdx.x] = b2[threadIdx.x];
    if (threadIdx.x < TD) bo[threadIdx.x] = bout[threadIdx.x];
    __syncthreads();
    int idx = blockIdx.x * 256 + threadIdx.x;
    if (idx >= N * TD) return;
    int n = idx / TD;
    int t = idx - n * TD;
    const float* a = agg + (size_t)n * HD;
    float acc = bo[t];
    #pragma unroll 8
    for (int k = 0; k < HD; ++k)
        acc += fmaxf(a[k] + bl[k], 0.f) * Wl[k * TD + t];
    out[idx] = acc;
}

extern "C" void kernel_launch(void* const* d_in, const int* in_sizes, int n_in,
                              void* d_out, int out_size, void* d_ws, size_t ws_size,
                              hipStream_t stream) {
    const float* x    = (const float*)d_in[0];
    const int*   ei   = (const int*)d_in[1];   // harness passes integers as int32
    const float* et   = (const float*)d_in[2];
    const float* W1   = (const float*)d_in[3];
    const float* b1   = (const float*)d_in[4];
    const float* W2   = (const float*)d_in[5];
    const float* b2   = (const float*)d_in[6];
    const float* Wout = (const float*)d_in[7];
    const float* bout = (const float*)d_in[8];
    float*       out  = (float*)d_out;

    int N = in_sizes[0] / FIN;
    int E = in_sizes[2];
    int NCHUNK = (N + CHUNK - 1) / CHUNK;          // 7 for N=100K
    int NB = (N + SCAN_ELEMS - 1) / SCAN_ELEMS;    // scan blocks (98)

    // --- workspace layout, 256B-aligned regions ---
    char*  base = (char*)d_ws;
    size_t ofs  = 0;
    auto alloc = [&](size_t bytes) -> char* {
        char* p = base + ofs;
        ofs = (ofs + bytes + 255) & ~(size_t)255;
        return p;
    };
    unsigned* tmaxb  = (unsigned*)alloc(64);
    float*    ebuf   = (float*)alloc((size_t)E * 4);        // decay
    float*    deg    = (float*)alloc((size_t)N * 4);        // deg -> dinv
    float*    deg2   = (float*)alloc((size_t)N * 4);        // deg2 -> dinv2
    int*      hist   = (int*)alloc((size_t)N * 4);
    int*      rowptr = (int*)alloc((size_t)(N + 1) * 4);
    int*      offb   = (int*)alloc((size_t)N * 4);
    int*      bsum   = (int*)alloc((size_t)1024 * 4);
    int*      boff   = (int*)alloc((size_t)1024 * 4);
    // priv region (deghist) is dead after k_deghist_red -> reuse for CSR sidx/sw
    size_t privBytes = (size_t)NCHUNK * SPLIT * CHUNK * 4;
    size_t csrBytes  = ((size_t)E * 4 + 255) & ~(size_t)255;
    size_t region    = 2 * (privBytes > csrBytes ? privBytes : csrBytes);
    char*  pbase     = alloc(region);
    float* privD = (float*)pbase;
    int*   privH = (int*)(pbase + privBytes);
    int*   sidx  = (int*)pbase;
    float* sw    = (float*)(pbase + csrBytes);
    float* gbuf  = (float*)alloc((size_t)N * HD * 4);
    float* agg   = (float*)alloc((size_t)N * HD * 4);

    int bN  = (N + 255) / 256;
    int bE  = (E + 255) / 256;
    int bT1 = (N + 63) / 64;
    int bT2 = (N + 127) / 128;
    int bWN = (N * HD + 255) / 256;

    k_init       <<<1,   64,  0, stream>>>(tmaxb);
    k_tmax       <<<256, 256, 0, stream>>>(et, tmaxb, E);
    k_deghist    <<<NCHUNK * SPLIT, 1024, 0, stream>>>(ei, et, tmaxb, ebuf, privD, privH, E, N);
    k_deghist_red<<<bN,  256, 0, stream>>>(privD, privH, deg, hist, N);
    k_rsqrt      <<<bN,  256, 0, stream>>>(deg, N);
    k_scan_a     <<<NB,  256, 0, stream>>>(hist, bsum, N);
    k_scan_b     <<<1,  1024, 0, stream>>>(bsum, boff, NB, rowptr + N);
    k_scan_c     <<<NB,  256, 0, stream>>>(hist, boff, rowptr, offb, N);
    k_ewfill     <<<bE,  256, 0, stream>>>(ei, ebuf, deg, offb, sidx, sw, E);
    k_deg2       <<<bN,  256, 0, stream>>>(rowptr, sw, deg2, N);
    k_rsqrt      <<<bN,  256, 0, stream>>>(deg2, N);

    k_mm1        <<<bT1, 256, 0, stream>>>(x, W1, deg2, gbuf, N);
    k_agg        <<<bWN, 256, 0, stream>>>(rowptr, sidx, sw, gbuf, deg2, agg, N);
    k_mm2        <<<bT2, 256, 0, stream>>>(agg, b1, W2, deg2, gbuf, N);
    k_agg        <<<bWN, 256, 0, stream>>>(rowptr, sidx, sw, gbuf, deg2, agg, N);
    k_out        <<<(N * TD + 255) / 256, 256, 0, stream>>>(agg, b2, Wout, bout, out, N);
}